// Round 2
// baseline (652.880 us; speedup 1.0000x reference)
//
#include <hip/hip_runtime.h>
#include <math.h>

// Qwen3.5 TopK Router, MI355X. fp64-accumulated GEMM for exact index ordering.
// logits = X(T,D) @ W(E,D)^T ; softmax over E; top-8 + renormalize.
// Out layout (all fp32): [T*E softmax-probs | T*K weights | T*K indices-as-float]
//
// Why fp64: indices are checked against a float64 numpy reference with an
// effectively-exact threshold. Sequential fp32 accumulation (~1e-5 abs err)
// flips near-tied rank boundaries (R0: absmax 7 on indices). fp64 error
// ~1e-13 << typical adjacent-logit gap (~0.04) -> ordering matches fp64 ref.
// Top-k selection runs on the fp64 LOGITS (monotone with softmax); only the
// emitted prob/weight VALUES are fp32 (threshold 0.02).

constexpr int T = 16384;
constexpr int D = 2048;
constexpr int E = 128;
constexpr int K = 8;

constexpr int BM = 64;   // tokens per block
constexpr int BK = 32;   // k-chunk

__global__ __launch_bounds__(256, 2)
void router_fused(const float* __restrict__ X,
                  const float* __restrict__ W,
                  float* __restrict__ out)
{
    __shared__ float As[BK][BM];   // [k][token]
    __shared__ float Bs[BK][E];    // [k][expert]

    const int tid = threadIdx.x;
    const int tx = tid & 15;       // expert group 0..15 (8 experts each)
    const int ty = tid >> 4;       // token group 0..15 (4 tokens each)
    const long t0 = (long)blockIdx.x * BM;

    double acc[4][8];
#pragma unroll
    for (int i = 0; i < 4; ++i)
#pragma unroll
        for (int j = 0; j < 8; ++j) acc[i][j] = 0.0;

    const int ar = tid >> 3;           // 0..31
    const int ac = (tid & 7) << 2;     // 0,4,...,28

    const float* Xp = X + (t0 + ar) * D + ac;
    const float* Wp = W + (long)ar * D + ac;

    for (int k0 = 0; k0 < D; k0 += BK) {
        float4 a0 = *(const float4*)(Xp + k0);
        float4 a1 = *(const float4*)(Xp + k0 + 32L * D);
        float4 b0 = *(const float4*)(Wp + k0);
        float4 b1 = *(const float4*)(Wp + k0 + 32L * D);
        float4 b2 = *(const float4*)(Wp + k0 + 64L * D);
        float4 b3 = *(const float4*)(Wp + k0 + 96L * D);

        __syncthreads();
        As[ac+0][ar] = a0.x; As[ac+1][ar] = a0.y; As[ac+2][ar] = a0.z; As[ac+3][ar] = a0.w;
        As[ac+0][ar+32] = a1.x; As[ac+1][ar+32] = a1.y; As[ac+2][ar+32] = a1.z; As[ac+3][ar+32] = a1.w;
        Bs[ac+0][ar]    = b0.x; Bs[ac+1][ar]    = b0.y; Bs[ac+2][ar]    = b0.z; Bs[ac+3][ar]    = b0.w;
        Bs[ac+0][ar+32] = b1.x; Bs[ac+1][ar+32] = b1.y; Bs[ac+2][ar+32] = b1.z; Bs[ac+3][ar+32] = b1.w;
        Bs[ac+0][ar+64] = b2.x; Bs[ac+1][ar+64] = b2.y; Bs[ac+2][ar+64] = b2.z; Bs[ac+3][ar+64] = b2.w;
        Bs[ac+0][ar+96] = b3.x; Bs[ac+1][ar+96] = b3.y; Bs[ac+2][ar+96] = b3.z; Bs[ac+3][ar+96] = b3.w;
        __syncthreads();

#pragma unroll
        for (int kk = 0; kk < BK; ++kk) {
            float4 av  = *(const float4*)&As[kk][ty << 2];
            float4 bv0 = *(const float4*)&Bs[kk][tx << 3];
            float4 bv1 = *(const float4*)&Bs[kk][(tx << 3) + 4];
            const double a[4] = {(double)av.x, (double)av.y, (double)av.z, (double)av.w};
            const double b[8] = {(double)bv0.x, (double)bv0.y, (double)bv0.z, (double)bv0.w,
                                 (double)bv1.x, (double)bv1.y, (double)bv1.z, (double)bv1.w};
#pragma unroll
            for (int i = 0; i < 4; ++i)
#pragma unroll
                for (int j = 0; j < 8; ++j)
                    acc[i][j] = fma(a[i], b[j], acc[i][j]);
        }
    }

    float* outL  = out;
    float* outWt = out + (long)T * E;
    float* outId = outWt + (long)T * K;

    // epilogue: each token row lives across 16 lanes (same ty, all tx) of ONE wave
    for (int i = 0; i < 4; ++i) {
        const long t = t0 + (ty << 2) + i;

        // max over experts (fp64, exact ordering irrelevant here but cheap)
        double m = acc[i][0];
#pragma unroll
        for (int j = 1; j < 8; ++j) m = fmax(m, acc[i][j]);
#pragma unroll
        for (int mask = 1; mask <= 8; mask <<= 1)
            m = fmax(m, __shfl_xor(m, mask, 64));

        // probabilities in fp32 (output threshold is 2% -- plenty)
        float e[8]; float s = 0.f;
#pragma unroll
        for (int j = 0; j < 8; ++j) { e[j] = __expf((float)(acc[i][j] - m)); s += e[j]; }
#pragma unroll
        for (int mask = 1; mask <= 8; mask <<= 1)
            s += __shfl_xor(s, mask, 64);
        const float inv = 1.f / s;

        float p[8];
#pragma unroll
        for (int j = 0; j < 8; ++j) p[j] = e[j] * inv;

        float4 st0 = {p[0], p[1], p[2], p[3]};
        float4 st1 = {p[4], p[5], p[6], p[7]};
        *(float4*)&outL[t * E + (tx << 3)]     = st0;
        *(float4*)&outL[t * E + (tx << 3) + 4] = st1;

        // top-8 on fp64 LOGITS (value desc, index asc) -- matches fp64 softmax order
        double v[8];
#pragma unroll
        for (int j = 0; j < 8; ++j) v[j] = acc[i][j];

        float pk[K]; int ik[K]; float tsum = 0.f;
#pragma unroll
        for (int r = 0; r < K; ++r) {
            double bv = -1.0e300; int bi = 0x7fffffff;
#pragma unroll
            for (int j = 0; j < 8; ++j) {
                const int idx = (tx << 3) + j;
                const bool better = (v[j] > bv) || (v[j] == bv && idx < bi);
                bv = better ? v[j] : bv;
                bi = better ? idx : bi;
            }
#pragma unroll
            for (int mask = 1; mask <= 8; mask <<= 1) {
                const double ov = __shfl_xor(bv, mask, 64);
                const int    oi = __shfl_xor(bi, mask, 64);
                const bool better = (ov > bv) || (ov == bv && oi < bi);
                bv = better ? ov : bv;
                bi = better ? oi : bi;
            }
            const float pw = __expf((float)(bv - m)) * inv;  // winner's prob, any lane
            pk[r] = pw; ik[r] = bi; tsum += pw;
            if ((bi >> 3) == tx) v[bi & 7] = -1.0e300;       // owner masks picked entry
        }

        if (tx == 0) {
            const float rinv = 1.f / tsum;
#pragma unroll
            for (int r = 0; r < K; ++r) {
                outWt[t * K + r] = pk[r] * rinv;
                outId[t * K + r] = (float)ik[r];
            }
        }
    }
}

extern "C" void kernel_launch(void* const* d_in, const int* in_sizes, int n_in,
                              void* d_out, int out_size, void* d_ws, size_t ws_size,
                              hipStream_t stream)
{
    const float* X = (const float*)d_in[0];
    const float* W = (const float*)d_in[1];
    float* out = (float*)d_out;
    router_fused<<<dim3(T / BM), dim3(256), 0, stream>>>(X, W, out);
}

// Round 3
// 496.252 us; speedup vs baseline: 1.3156x; 1.3156x over previous
//
#include <hip/hip_runtime.h>
#include <math.h>

// Qwen3.5 TopK Router, MI355X. fp64-accumulated GEMM for exact index ordering.
// logits = X(T,D) @ W(E,D)^T ; softmax over E; top-8 + renormalize.
// Out layout (all fp32): [T*E softmax-probs | T*K weights | T*K indices-as-float]
//
// R3 changes vs R2 (545 us, VALUBusy 30%, 3.88e7 LDS conflicts):
//  - XOR bank swizzle phi(k)=((k>>2)&3)<<3 on LDS column index:
//    transposed scalar stores go 8-way -> 2-way (free).
//  - software prefetch: next tile's global loads issued before compute,
//    so ~900cyc HBM latency overlaps ~5000cyc of dfma.
//  - __launch_bounds__(256,1): grid==256 blocks==1 block/CU, occupancy is
//    grid-limited; give the allocator room for prefetch registers.

constexpr int T = 16384;
constexpr int D = 2048;
constexpr int E = 128;
constexpr int K = 8;

constexpr int BM = 64;   // tokens per block
constexpr int BK = 32;   // k-chunk

__device__ __forceinline__ int phi_of(int k) { return ((k >> 2) & 3) << 3; }

__global__ __launch_bounds__(256, 1)
void router_fused(const float* __restrict__ X,
                  const float* __restrict__ W,
                  float* __restrict__ out)
{
    __shared__ float As[BK * BM];   // [k][token^phi(k)]
    __shared__ float Bs[BK * E];    // [k][expert^phi(k)]

    const int tid = threadIdx.x;
    const int tx = tid & 15;       // expert group 0..15 (8 experts each)
    const int ty = tid >> 4;       // token group 0..15 (4 tokens each)
    const long t0 = (long)blockIdx.x * BM;

    double acc[4][8];
#pragma unroll
    for (int i = 0; i < 4; ++i)
#pragma unroll
        for (int j = 0; j < 8; ++j) acc[i][j] = 0.0;

    const int ar = tid >> 3;           // 0..31
    const int ac = (tid & 7) << 2;     // 0,4,...,28  (ac % 4 == 0)
    const int phiS = phi_of(ac);       // same phi for all 4 k's of a float4

    const float* Xp = X + (t0 + ar) * D + ac;
    const float* Wp = W + (long)ar * D + ac;

    // prologue: load tile 0
    float4 a0 = *(const float4*)(Xp);
    float4 a1 = *(const float4*)(Xp + 32L * D);
    float4 b0 = *(const float4*)(Wp);
    float4 b1 = *(const float4*)(Wp + 32L * D);
    float4 b2 = *(const float4*)(Wp + 64L * D);
    float4 b3 = *(const float4*)(Wp + 96L * D);

    for (int k0 = 0; k0 < D; k0 += BK) {
        __syncthreads();   // previous tile fully consumed
        {
            const int cA0 = ar ^ phiS, cA1 = (ar + 32) ^ phiS;
            As[(ac+0)*BM + cA0] = a0.x; As[(ac+1)*BM + cA0] = a0.y;
            As[(ac+2)*BM + cA0] = a0.z; As[(ac+3)*BM + cA0] = a0.w;
            As[(ac+0)*BM + cA1] = a1.x; As[(ac+1)*BM + cA1] = a1.y;
            As[(ac+2)*BM + cA1] = a1.z; As[(ac+3)*BM + cA1] = a1.w;
            const int cB0 = ar ^ phiS, cB1 = (ar+32) ^ phiS,
                      cB2 = (ar+64) ^ phiS, cB3 = (ar+96) ^ phiS;
            Bs[(ac+0)*E + cB0] = b0.x; Bs[(ac+1)*E + cB0] = b0.y;
            Bs[(ac+2)*E + cB0] = b0.z; Bs[(ac+3)*E + cB0] = b0.w;
            Bs[(ac+0)*E + cB1] = b1.x; Bs[(ac+1)*E + cB1] = b1.y;
            Bs[(ac+2)*E + cB1] = b1.z; Bs[(ac+3)*E + cB1] = b1.w;
            Bs[(ac+0)*E + cB2] = b2.x; Bs[(ac+1)*E + cB2] = b2.y;
            Bs[(ac+2)*E + cB2] = b2.z; Bs[(ac+3)*E + cB2] = b2.w;
            Bs[(ac+0)*E + cB3] = b3.x; Bs[(ac+1)*E + cB3] = b3.y;
            Bs[(ac+2)*E + cB3] = b3.z; Bs[(ac+3)*E + cB3] = b3.w;
        }
        __syncthreads();

        // prefetch next tile while computing this one
        const int kn = k0 + BK;
        if (kn < D) {
            a0 = *(const float4*)(Xp + kn);
            a1 = *(const float4*)(Xp + kn + 32L * D);
            b0 = *(const float4*)(Wp + kn);
            b1 = *(const float4*)(Wp + kn + 32L * D);
            b2 = *(const float4*)(Wp + kn + 64L * D);
            b3 = *(const float4*)(Wp + kn + 96L * D);
        }

#pragma unroll
        for (int kk = 0; kk < BK; ++kk) {
            const int phi = phi_of(kk);
            float4 av  = *(const float4*)&As[kk*BM + ((ty << 2) ^ phi)];
            float4 bv0 = *(const float4*)&Bs[kk*E + ((tx << 3) ^ phi)];
            float4 bv1 = *(const float4*)&Bs[kk*E + (((tx << 3) + 4) ^ phi)];
            const double a[4] = {(double)av.x, (double)av.y, (double)av.z, (double)av.w};
            const double b[8] = {(double)bv0.x, (double)bv0.y, (double)bv0.z, (double)bv0.w,
                                 (double)bv1.x, (double)bv1.y, (double)bv1.z, (double)bv1.w};
#pragma unroll
            for (int i = 0; i < 4; ++i)
#pragma unroll
                for (int j = 0; j < 8; ++j)
                    acc[i][j] = fma(a[i], b[j], acc[i][j]);
        }
    }

    float* outL  = out;
    float* outWt = out + (long)T * E;
    float* outId = outWt + (long)T * K;

    // epilogue: each token row lives across 16 lanes (same ty, all tx) of ONE wave
    for (int i = 0; i < 4; ++i) {
        const long t = t0 + (ty << 2) + i;

        double m = acc[i][0];
#pragma unroll
        for (int j = 1; j < 8; ++j) m = fmax(m, acc[i][j]);
#pragma unroll
        for (int mask = 1; mask <= 8; mask <<= 1)
            m = fmax(m, __shfl_xor(m, mask, 64));

        float e[8]; float s = 0.f;
#pragma unroll
        for (int j = 0; j < 8; ++j) { e[j] = __expf((float)(acc[i][j] - m)); s += e[j]; }
#pragma unroll
        for (int mask = 1; mask <= 8; mask <<= 1)
            s += __shfl_xor(s, mask, 64);
        const float inv = 1.f / s;

        float p[8];
#pragma unroll
        for (int j = 0; j < 8; ++j) p[j] = e[j] * inv;

        float4 st0 = {p[0], p[1], p[2], p[3]};
        float4 st1 = {p[4], p[5], p[6], p[7]};
        *(float4*)&outL[t * E + (tx << 3)]     = st0;
        *(float4*)&outL[t * E + (tx << 3) + 4] = st1;

        // top-8 on fp64 LOGITS (value desc, index asc) == jax.lax.top_k order
        double v[8];
#pragma unroll
        for (int j = 0; j < 8; ++j) v[j] = acc[i][j];

        float pk[K]; int ik[K]; float tsum = 0.f;
#pragma unroll
        for (int r = 0; r < K; ++r) {
            double bv = -1.0e300; int bi = 0x7fffffff;
#pragma unroll
            for (int j = 0; j < 8; ++j) {
                const int idx = (tx << 3) + j;
                const bool better = (v[j] > bv) || (v[j] == bv && idx < bi);
                bv = better ? v[j] : bv;
                bi = better ? idx : bi;
            }
#pragma unroll
            for (int mask = 1; mask <= 8; mask <<= 1) {
                const double ov = __shfl_xor(bv, mask, 64);
                const int    oi = __shfl_xor(bi, mask, 64);
                const bool better = (ov > bv) || (ov == bv && oi < bi);
                bv = better ? ov : bv;
                bi = better ? oi : bi;
            }
            const float pw = __expf((float)(bv - m)) * inv;
            pk[r] = pw; ik[r] = bi; tsum += pw;
            if ((bi >> 3) == tx) v[bi & 7] = -1.0e300;
        }

        if (tx == 0) {
            const float rinv = 1.f / tsum;
#pragma unroll
            for (int r = 0; r < K; ++r) {
                outWt[t * K + r] = pk[r] * rinv;
                outId[t * K + r] = (float)ik[r];
            }
        }
    }
}

extern "C" void kernel_launch(void* const* d_in, const int* in_sizes, int n_in,
                              void* d_out, int out_size, void* d_ws, size_t ws_size,
                              hipStream_t stream)
{
    const float* X = (const float*)d_in[0];
    const float* W = (const float*)d_in[1];
    float* out = (float*)d_out;
    router_fused<<<dim3(T / BM), dim3(256), 0, stream>>>(X, W, out);
}

// Round 4
// 433.729 us; speedup vs baseline: 1.5053x; 1.1442x over previous
//
#include <hip/hip_runtime.h>
#include <math.h>

// Qwen3.5 TopK Router, MI355X. fp64-accumulated GEMM for exact index ordering.
// logits = X(T,D) @ W(E,D)^T ; softmax over E; top-8 + renormalize.
// Out layout (all fp32): [T*E softmax-probs | T*K weights | T*K indices-as-float]
//
// R4 changes vs R3 (392 us, VALUBusy 43%, Occupancy 11.8% = 1 wave/SIMD):
//  - split-K x2 INSIDE a 512-thread block: waves 0-3 take k in [0,1024),
//    waves 4-7 take [1024,2048). Grid stays 256 (=1 block/CU) but now
//    8 waves/CU = 2 waves/SIMD -> issue gaps (LDS latency, barrier drain)
//    covered by the co-resident wave. Thread tile stays 4x8 (best cvt:dfma).
//  - cross-group fp64 reduction through LDS once at the end (64KB exchange
//    buffer aliased over the dead tile buffers), then R3's epilogue on
//    group 0 unchanged. One extra fp64 add per acc: error ~1e-13, safe.

constexpr int T = 16384;
constexpr int D = 2048;
constexpr int E = 128;
constexpr int K = 8;

constexpr int BM = 64;   // tokens per block
constexpr int BK = 32;   // k-chunk
constexpr int D2 = D / 2;

__device__ __forceinline__ int phi_of(int k) { return ((k >> 2) & 3) << 3; }

__global__ __launch_bounds__(512, 2)
void router_fused(const float* __restrict__ X,
                  const float* __restrict__ W,
                  float* __restrict__ out)
{
    __shared__ char smem[65536];
    // per-group tile buffers: 24KB each (As 8KB + Bs 16KB), groups side by side
    // exchange buffer: all 64KB as doubles (aliased; used only after last tile)

    const int tid = threadIdx.x;
    const int g   = tid >> 8;        // k-split group 0/1
    const int l   = tid & 255;       // lane-id within group
    const int tx = l & 15;           // expert group 0..15 (8 experts each)
    const int ty = l >> 4;           // token group 0..15 (4 tokens each)
    const long t0 = (long)blockIdx.x * BM;

    float* As = (float*)(smem + g * 24576);
    float* Bs = As + BK * BM;
    double* ex = (double*)smem;

    double acc[4][8];
#pragma unroll
    for (int i = 0; i < 4; ++i)
#pragma unroll
        for (int j = 0; j < 8; ++j) acc[i][j] = 0.0;

    const int ar = l >> 3;             // 0..31
    const int ac = (l & 7) << 2;       // 0,4,...,28
    const int phiS = phi_of(ac);

    const float* Xp = X + (t0 + ar) * D + (long)g * D2 + ac;
    const float* Wp = W + (long)ar * D + (long)g * D2 + ac;

    // prologue: load tile 0 of this group's k-half
    float4 a0 = *(const float4*)(Xp);
    float4 a1 = *(const float4*)(Xp + 32L * D);
    float4 b0 = *(const float4*)(Wp);
    float4 b1 = *(const float4*)(Wp + 32L * D);
    float4 b2 = *(const float4*)(Wp + 64L * D);
    float4 b3 = *(const float4*)(Wp + 96L * D);

    for (int k0 = 0; k0 < D2; k0 += BK) {
        __syncthreads();   // previous tile fully consumed (both groups)
        {
            const int cA0 = ar ^ phiS, cA1 = (ar + 32) ^ phiS;
            As[(ac+0)*BM + cA0] = a0.x; As[(ac+1)*BM + cA0] = a0.y;
            As[(ac+2)*BM + cA0] = a0.z; As[(ac+3)*BM + cA0] = a0.w;
            As[(ac+0)*BM + cA1] = a1.x; As[(ac+1)*BM + cA1] = a1.y;
            As[(ac+2)*BM + cA1] = a1.z; As[(ac+3)*BM + cA1] = a1.w;
            const int cB0 = ar ^ phiS, cB1 = (ar+32) ^ phiS,
                      cB2 = (ar+64) ^ phiS, cB3 = (ar+96) ^ phiS;
            Bs[(ac+0)*E + cB0] = b0.x; Bs[(ac+1)*E + cB0] = b0.y;
            Bs[(ac+2)*E + cB0] = b0.z; Bs[(ac+3)*E + cB0] = b0.w;
            Bs[(ac+0)*E + cB1] = b1.x; Bs[(ac+1)*E + cB1] = b1.y;
            Bs[(ac+2)*E + cB1] = b1.z; Bs[(ac+3)*E + cB1] = b1.w;
            Bs[(ac+0)*E + cB2] = b2.x; Bs[(ac+1)*E + cB2] = b2.y;
            Bs[(ac+2)*E + cB2] = b2.z; Bs[(ac+3)*E + cB2] = b2.w;
            Bs[(ac+0)*E + cB3] = b3.x; Bs[(ac+1)*E + cB3] = b3.y;
            Bs[(ac+2)*E + cB3] = b3.z; Bs[(ac+3)*E + cB3] = b3.w;
        }
        __syncthreads();

        // prefetch next tile while computing this one
        const int kn = k0 + BK;
        if (kn < D2) {
            a0 = *(const float4*)(Xp + kn);
            a1 = *(const float4*)(Xp + kn + 32L * D);
            b0 = *(const float4*)(Wp + kn);
            b1 = *(const float4*)(Wp + kn + 32L * D);
            b2 = *(const float4*)(Wp + kn + 64L * D);
            b3 = *(const float4*)(Wp + kn + 96L * D);
        }

#pragma unroll
        for (int kk = 0; kk < BK; ++kk) {
            const int phi = phi_of(kk);
            float4 av  = *(const float4*)&As[kk*BM + ((ty << 2) ^ phi)];
            float4 bv0 = *(const float4*)&Bs[kk*E + ((tx << 3) ^ phi)];
            float4 bv1 = *(const float4*)&Bs[kk*E + (((tx << 3) + 4) ^ phi)];
            const double a[4] = {(double)av.x, (double)av.y, (double)av.z, (double)av.w};
            const double b[8] = {(double)bv0.x, (double)bv0.y, (double)bv0.z, (double)bv0.w,
                                 (double)bv1.x, (double)bv1.y, (double)bv1.z, (double)bv1.w};
#pragma unroll
            for (int i = 0; i < 4; ++i)
#pragma unroll
                for (int j = 0; j < 8; ++j)
                    acc[i][j] = fma(a[i], b[j], acc[i][j]);
        }
    }

    // ---- cross-group reduction: group 1 -> LDS -> group 0 adds ----
    __syncthreads();                  // both groups done reading tile buffers
    if (g == 1) {
#pragma unroll
        for (int i = 0; i < 4; ++i)
#pragma unroll
            for (int j = 0; j < 8; ++j)
                ex[((ty << 2) + i) * E + (tx << 3) + j] = acc[i][j];
    }
    __syncthreads();
    if (g == 1) return;               // no further barriers below
#pragma unroll
    for (int i = 0; i < 4; ++i)
#pragma unroll
        for (int j = 0; j < 8; ++j)
            acc[i][j] += ex[((ty << 2) + i) * E + (tx << 3) + j];

    float* outL  = out;
    float* outWt = out + (long)T * E;
    float* outId = outWt + (long)T * K;

    // epilogue (group 0 only): each token row = 16 lanes (same ty, all tx) of one wave
    for (int i = 0; i < 4; ++i) {
        const long t = t0 + (ty << 2) + i;

        double m = acc[i][0];
#pragma unroll
        for (int j = 1; j < 8; ++j) m = fmax(m, acc[i][j]);
#pragma unroll
        for (int mask = 1; mask <= 8; mask <<= 1)
            m = fmax(m, __shfl_xor(m, mask, 64));

        float e[8]; float s = 0.f;
#pragma unroll
        for (int j = 0; j < 8; ++j) { e[j] = __expf((float)(acc[i][j] - m)); s += e[j]; }
#pragma unroll
        for (int mask = 1; mask <= 8; mask <<= 1)
            s += __shfl_xor(s, mask, 64);
        const float inv = 1.f / s;

        float p[8];
#pragma unroll
        for (int j = 0; j < 8; ++j) p[j] = e[j] * inv;

        float4 st0 = {p[0], p[1], p[2], p[3]};
        float4 st1 = {p[4], p[5], p[6], p[7]};
        *(float4*)&outL[t * E + (tx << 3)]     = st0;
        *(float4*)&outL[t * E + (tx << 3) + 4] = st1;

        // top-8 on fp64 LOGITS (value desc, index asc) == jax.lax.top_k order
        double v[8];
#pragma unroll
        for (int j = 0; j < 8; ++j) v[j] = acc[i][j];

        float pk[K]; int ik[K]; float tsum = 0.f;
#pragma unroll
        for (int r = 0; r < K; ++r) {
            double bv = -1.0e300; int bi = 0x7fffffff;
#pragma unroll
            for (int j = 0; j < 8; ++j) {
                const int idx = (tx << 3) + j;
                const bool better = (v[j] > bv) || (v[j] == bv && idx < bi);
                bv = better ? v[j] : bv;
                bi = better ? idx : bi;
            }
#pragma unroll
            for (int mask = 1; mask <= 8; mask <<= 1) {
                const double ov = __shfl_xor(bv, mask, 64);
                const int    oi = __shfl_xor(bi, mask, 64);
                const bool better = (ov > bv) || (ov == bv && oi < bi);
                bv = better ? ov : bv;
                bi = better ? oi : bi;
            }
            const float pw = __expf((float)(bv - m)) * inv;
            pk[r] = pw; ik[r] = bi; tsum += pw;
            if ((bi >> 3) == tx) v[bi & 7] = -1.0e300;
        }

        if (tx == 0) {
            const float rinv = 1.f / tsum;
#pragma unroll
            for (int r = 0; r < K; ++r) {
                outWt[t * K + r] = pk[r] * rinv;
                outId[t * K + r] = (float)ik[r];
            }
        }
    }
}

extern "C" void kernel_launch(void* const* d_in, const int* in_sizes, int n_in,
                              void* d_out, int out_size, void* d_ws, size_t ws_size,
                              hipStream_t stream)
{
    const float* X = (const float*)d_in[0];
    const float* W = (const float*)d_in[1];
    float* out = (float*)d_out;
    router_fused<<<dim3(T / BM), dim3(512), 0, stream>>>(X, W, out);
}